// Round 6
// baseline (408.221 us; speedup 1.0000x reference)
//
#include <hip/hip_runtime.h>
#include <stdint.h>
#include <stddef.h>

#define B_ 2
#define S_ 2048
#define D_ 1024
#define H_ 16
#define HD_ 64
#define FF_ 4096

typedef unsigned short u16;
typedef __attribute__((ext_vector_type(8))) short bf16x8;
typedef __attribute__((ext_vector_type(4))) float f32x4;

__device__ __forceinline__ u16 f2bf(float f) {
  unsigned u = __float_as_uint(f);
  u += 0x7fffu + ((u >> 16) & 1u);
  return (u16)(u >> 16);
}

__device__ __forceinline__ f32x4 mfma16(bf16x8 a, bf16x8 b, f32x4 c) {
  return __builtin_amdgcn_mfma_f32_16x16x32_bf16(a, b, c, 0, 0, 0);
}

__device__ __forceinline__ void gload16(const void* g, void* l) {
  __builtin_amdgcn_global_load_lds(
      (const __attribute__((address_space(1))) void*)g,
      (__attribute__((address_space(3))) void*)l, 16, 0, 0);
}

// XCD-aware block swizzle: bid%8 -> XCD (round-robin dispatch); each XCD gets
// a contiguous band of m-tiles (A stays L2-resident), 4 consecutive blocks
// share each B-tile. Bijective when gridDim.x % 8 == 0.
__device__ __forceinline__ void swizzle_mn(int& mt, int& nt) {
  int gm = gridDim.x;
  if ((gm & 7) == 0) {
    int bid = blockIdx.y * gm + blockIdx.x;
    int mper = gm >> 3;
    int xcd = bid & 7, idx = bid >> 3;
    mt = xcd * mper + (idx % mper);
    nt = idx / mper;
  } else {
    mt = blockIdx.x;
    nt = blockIdx.y;
  }
}

// ---------------- elementwise fp32 -> bf16 ----------------
__global__ __launch_bounds__(256) void cvt_kernel(const float* __restrict__ src,
                                                  u16* __restrict__ dst, int n) {
  int i = (blockIdx.x * 256 + threadIdx.x) * 4;
  if (i >= n) return;
  float4 v = *(const float4*)(src + i);
  ushort4 o = { f2bf(v.x), f2bf(v.y), f2bf(v.z), f2bf(v.w) };
  *(ushort4*)(dst + i) = o;
}

// ---------------- transpose + convert: W (K x N) fp32 -> WT (N x K) bf16 ----
__global__ __launch_bounds__(256) void transpose_cvt_kernel(
    const float* __restrict__ W, u16* __restrict__ WT, int K, int N) {
  __shared__ u16 t[32][33];
  int k0 = blockIdx.x * 32;
  int n0 = blockIdx.y * 32;
  int tid = threadIdx.x;
  int r = tid >> 3;         // 0..31
  int c = (tid & 7) << 2;   // 0..28
  float4 v = *(const float4*)(W + (size_t)(k0 + r) * N + n0 + c);
  t[r][c + 0] = f2bf(v.x); t[r][c + 1] = f2bf(v.y);
  t[r][c + 2] = f2bf(v.z); t[r][c + 3] = f2bf(v.w);
  __syncthreads();
  ushort4 o;
  o.x = t[c + 0][r]; o.y = t[c + 1][r]; o.z = t[c + 2][r]; o.w = t[c + 3][r];
  *(ushort4*)(WT + (size_t)(n0 + r) * K + k0 + c) = o;
}

// ---------------- GEMM 128x128, out bf16 + relu (+bias)  [ffn1] ------------
__global__ __launch_bounds__(256) void gemm_bt_relu(
    const u16* __restrict__ A, const u16* __restrict__ BT,
    const float* __restrict__ bias, u16* __restrict__ outp,
    int M, int N, int K) {
  __shared__ __align__(16) u16 As[128 * 32];
  __shared__ __align__(16) u16 Bs[128 * 32];
  int tid = threadIdx.x;
  int lane = tid & 63;
  int wave = tid >> 6;
  int quad = lane >> 4;
  int l16 = lane & 15;
  int mt, nt;
  swizzle_mn(mt, nt);
  int m0 = mt * 128;
  int n0 = nt * 128;
  int wm = (wave >> 1) * 64;
  int wn = (wave & 1) * 64;

  f32x4 zero = {0.f, 0.f, 0.f, 0.f};
  f32x4 acc[4][4];
#pragma unroll
  for (int i = 0; i < 4; i++)
#pragma unroll
    for (int j = 0; j < 4; j++) acc[i][j] = zero;

  int c0 = tid, c1 = tid + 256;
  const u16* ga0 = A + (size_t)(m0 + (c0 >> 2)) * K + (c0 & 3) * 8;
  const u16* ga1 = A + (size_t)(m0 + (c1 >> 2)) * K + (c1 & 3) * 8;
  const u16* gb0 = BT + (size_t)(n0 + (c0 >> 2)) * K + (c0 & 3) * 8;
  const u16* gb1 = BT + (size_t)(n0 + (c1 >> 2)) * K + (c1 & 3) * 8;

  for (int k0 = 0; k0 < K; k0 += 32) {
    gload16(ga0 + k0, &As[c0 * 8]);
    gload16(ga1 + k0, &As[c1 * 8]);
    gload16(gb0 + k0, &Bs[c0 * 8]);
    gload16(gb1 + k0, &Bs[c1 * 8]);
    __syncthreads();
    bf16x8 af[4], bfr[4];
#pragma unroll
    for (int i = 0; i < 4; i++)
      af[i] = *(const bf16x8*)&As[(wm + i * 16 + l16) * 32 + quad * 8];
#pragma unroll
    for (int j = 0; j < 4; j++)
      bfr[j] = *(const bf16x8*)&Bs[(wn + j * 16 + l16) * 32 + quad * 8];
#pragma unroll
    for (int i = 0; i < 4; i++)
#pragma unroll
      for (int j = 0; j < 4; j++)
        acc[i][j] = mfma16(af[i], bfr[j], acc[i][j]);
    __syncthreads();
  }

#pragma unroll
  for (int j = 0; j < 4; j++) {
    int gcol = n0 + wn + j * 16 + l16;
    float bv = bias[gcol];
#pragma unroll
    for (int i = 0; i < 4; i++) {
#pragma unroll
      for (int r = 0; r < 4; r++) {
        int grow = m0 + wm + i * 16 + quad * 4 + r;
        float val = acc[i][j][r] + bv;
        outp[(size_t)grow * N + gcol] = f2bf(val > 0.f ? val : 0.f);
      }
    }
  }
}

// ---------------- GEMM 128x128 split-K x2, separate fp32 outputs -----------
// grid.z: z covers K-range [z*Kc, (z+1)*Kc); writes outp + z*M*N.
// No atomics/memsets; partials summed inside the LN kernel. Bias at z=0.
__global__ __launch_bounds__(256) void gemm_bt_sk2(
    const u16* __restrict__ A, const u16* __restrict__ BT,
    const float* __restrict__ bias, float* __restrict__ outp,
    int M, int N, int K, int Kc) {
  __shared__ __align__(16) u16 As[128 * 32];
  __shared__ __align__(16) u16 Bs[128 * 32];
  int tid = threadIdx.x;
  int lane = tid & 63;
  int wave = tid >> 6;
  int quad = lane >> 4;
  int l16 = lane & 15;
  int mt, nt;
  swizzle_mn(mt, nt);
  int m0 = mt * 128;
  int n0 = nt * 128;
  int kb = blockIdx.z * Kc;
  int wm = (wave >> 1) * 64;
  int wn = (wave & 1) * 64;

  f32x4 zero = {0.f, 0.f, 0.f, 0.f};
  f32x4 acc[4][4];
#pragma unroll
  for (int i = 0; i < 4; i++)
#pragma unroll
    for (int j = 0; j < 4; j++) acc[i][j] = zero;

  int c0 = tid, c1 = tid + 256;
  const u16* ga0 = A + (size_t)(m0 + (c0 >> 2)) * K + (c0 & 3) * 8 + kb;
  const u16* ga1 = A + (size_t)(m0 + (c1 >> 2)) * K + (c1 & 3) * 8 + kb;
  const u16* gb0 = BT + (size_t)(n0 + (c0 >> 2)) * K + (c0 & 3) * 8 + kb;
  const u16* gb1 = BT + (size_t)(n0 + (c1 >> 2)) * K + (c1 & 3) * 8 + kb;

  for (int k0 = 0; k0 < Kc; k0 += 32) {
    gload16(ga0 + k0, &As[c0 * 8]);
    gload16(ga1 + k0, &As[c1 * 8]);
    gload16(gb0 + k0, &Bs[c0 * 8]);
    gload16(gb1 + k0, &Bs[c1 * 8]);
    __syncthreads();
    bf16x8 af[4], bfr[4];
#pragma unroll
    for (int i = 0; i < 4; i++)
      af[i] = *(const bf16x8*)&As[(wm + i * 16 + l16) * 32 + quad * 8];
#pragma unroll
    for (int j = 0; j < 4; j++)
      bfr[j] = *(const bf16x8*)&Bs[(wn + j * 16 + l16) * 32 + quad * 8];
#pragma unroll
    for (int i = 0; i < 4; i++)
#pragma unroll
      for (int j = 0; j < 4; j++)
        acc[i][j] = mfma16(af[i], bfr[j], acc[i][j]);
    __syncthreads();
  }

  float* outz = outp + (size_t)blockIdx.z * M * N;
  float biasmul = (blockIdx.z == 0) ? 1.f : 0.f;
#pragma unroll
  for (int j = 0; j < 4; j++) {
    int gcol = n0 + wn + j * 16 + l16;
    float bv = bias[gcol] * biasmul;
#pragma unroll
    for (int i = 0; i < 4; i++) {
#pragma unroll
      for (int r = 0; r < 4; r++) {
        int grow = m0 + wm + i * 16 + quad * 4 + r;
        outz[(size_t)grow * N + gcol] = acc[i][j][r] + bv;
      }
    }
  }
}

// ---------------- fused QKV GEMM (q pre-scaled by 1/sqrt(HD)*log2e) --------
__global__ __launch_bounds__(256) void gemm_qkv(
    const u16* __restrict__ A, const u16* __restrict__ BT,
    const float* __restrict__ bq, const float* __restrict__ bk,
    const float* __restrict__ bvp,
    u16* __restrict__ qb, u16* __restrict__ kb, u16* __restrict__ vb) {
  const int K = 1024;
  __shared__ __align__(16) u16 As[128 * 32];
  __shared__ __align__(16) u16 Bs[128 * 32];
  int tid = threadIdx.x;
  int lane = tid & 63;
  int wave = tid >> 6;
  int quad = lane >> 4;
  int l16 = lane & 15;
  int mt, nt;
  swizzle_mn(mt, nt);
  int m0 = mt * 128;
  int n0 = nt * 128;
  int wm = (wave >> 1) * 64;
  int wn = (wave & 1) * 64;

  f32x4 zero = {0.f, 0.f, 0.f, 0.f};
  f32x4 acc[4][4];
#pragma unroll
  for (int i = 0; i < 4; i++)
#pragma unroll
    for (int j = 0; j < 4; j++) acc[i][j] = zero;

  int c0 = tid, c1 = tid + 256;
  const u16* ga0 = A + (size_t)(m0 + (c0 >> 2)) * K + (c0 & 3) * 8;
  const u16* ga1 = A + (size_t)(m0 + (c1 >> 2)) * K + (c1 & 3) * 8;
  const u16* gb0 = BT + (size_t)(n0 + (c0 >> 2)) * K + (c0 & 3) * 8;
  const u16* gb1 = BT + (size_t)(n0 + (c1 >> 2)) * K + (c1 & 3) * 8;

  for (int k0 = 0; k0 < K; k0 += 32) {
    gload16(ga0 + k0, &As[c0 * 8]);
    gload16(ga1 + k0, &As[c1 * 8]);
    gload16(gb0 + k0, &Bs[c0 * 8]);
    gload16(gb1 + k0, &Bs[c1 * 8]);
    __syncthreads();
    bf16x8 af[4], bfr[4];
#pragma unroll
    for (int i = 0; i < 4; i++)
      af[i] = *(const bf16x8*)&As[(wm + i * 16 + l16) * 32 + quad * 8];
#pragma unroll
    for (int j = 0; j < 4; j++)
      bfr[j] = *(const bf16x8*)&Bs[(wn + j * 16 + l16) * 32 + quad * 8];
#pragma unroll
    for (int i = 0; i < 4; i++)
#pragma unroll
      for (int j = 0; j < 4; j++)
        acc[i][j] = mfma16(af[i], bfr[j], acc[i][j]);
    __syncthreads();
  }

  int region = n0 >> 10;                       // uniform per block
  const float* bias = region == 0 ? bq : (region == 1 ? bk : bvp);
  u16* outp = region == 0 ? qb : (region == 1 ? kb : vb);
  float scale = region == 0 ? 0.125f * 1.4426950408889634f : 1.f;

#pragma unroll
  for (int j = 0; j < 4; j++) {
    int gcol = (n0 & 1023) + wn + j * 16 + l16;  // col within region
    float bv = bias[gcol];
    int h = gcol >> 6, hd = gcol & 63;
#pragma unroll
    for (int i = 0; i < 4; i++) {
#pragma unroll
      for (int r = 0; r < 4; r++) {
        int grow = m0 + wm + i * 16 + quad * 4 + r;
        float val = (acc[i][j][r] + bv) * scale;
        int b = grow >> 11, s = grow & 2047;
        if (region < 2) {
          outp[(((size_t)(b * H_ + h)) * S_ + s) * HD_ + hd] = f2bf(val);
        } else {
          outp[(((size_t)(b * H_ + h)) * HD_ + hd) * S_ + s] = f2bf(val);
        }
      }
    }
  }
}

// ---------------- flash attention, MQ=32/wave, LDS-staged ------------------
// Each wave handles 32 q-rows (two 16-row groups A,B sharing K/V frag reads);
// block covers 128 q-rows. K staged row-permuted (even keys -> rows 0..15,
// odd -> 16..31 per 32-group) so P-writes are packed b32. Q pre-scaled.
__global__ __launch_bounds__(256, 4) void attn_kernel(
    const u16* __restrict__ q, const u16* __restrict__ k,
    const u16* __restrict__ vt, const int* __restrict__ mask,
    u16* __restrict__ ao) {
  __shared__ __align__(16) u16 Ks[64 * 72];
  __shared__ __align__(16) u16 Vs[64 * 72];
  __shared__ __align__(16) u16 Ps[4][32 * 72];
  int tid = threadIdx.x;
  int lane = tid & 63;
  int wave = tid >> 6;
  int quad = lane >> 4;
  int l16 = lane & 15;
  int bh = blockIdx.y;
  int b = bh >> 4;
  int h = bh & 15;
  int qrow0 = blockIdx.x * 128 + wave * 32;

  const u16* qh = q + (size_t)bh * S_ * HD_;
  const u16* kh = k + (size_t)bh * S_ * HD_;
  const u16* vh = vt + (size_t)bh * HD_ * S_;

  bf16x8 qfA0 = *(const bf16x8*)(qh + (size_t)(qrow0 + l16) * HD_ + quad * 8);
  bf16x8 qfA1 = *(const bf16x8*)(qh + (size_t)(qrow0 + l16) * HD_ + 32 + quad * 8);
  bf16x8 qfB0 = *(const bf16x8*)(qh + (size_t)(qrow0 + 16 + l16) * HD_ + quad * 8);
  bf16x8 qfB1 = *(const bf16x8*)(qh + (size_t)(qrow0 + 16 + l16) * HD_ + 32 + quad * 8);

  int sr = tid >> 3, sc = tid & 7;
  const u16* kg0 = kh + sr * HD_ + sc * 8;
  const u16* kg1 = kh + (sr + 32) * HD_ + sc * 8;
  const u16* vg0 = vh + (size_t)sr * S_ + sc * 8;
  const u16* vg1 = vh + (size_t)(sr + 32) * S_ + sc * 8;
  int kr0 = (sr & 1) * 16 + (sr >> 1);   // permuted row for key sr
  int ko0 = kr0 * 72 + sc * 8;
  int ko1 = (32 + kr0) * 72 + sc * 8;    // key sr+32 -> group 1
  int vo0 = sr * 72 + sc * 8;
  int vo1 = (sr + 32) * 72 + sc * 8;
  const int* mrow = mask + b * S_ + 2 * l16;

  float l_pA[4] = {0.f, 0.f, 0.f, 0.f};
  float l_pB[4] = {0.f, 0.f, 0.f, 0.f};
  f32x4 zero = {0.f, 0.f, 0.f, 0.f};
  f32x4 o_accA[4], o_accB[4];
#pragma unroll
  for (int c = 0; c < 4; c++) { o_accA[c] = zero; o_accB[c] = zero; }

  u16* pw = &Ps[wave][0];

  for (int kt = 0; kt < S_; kt += 64) {
    bf16x8 kv0 = *(const bf16x8*)(kg0 + (size_t)kt * HD_);
    bf16x8 kv1 = *(const bf16x8*)(kg1 + (size_t)kt * HD_);
    bf16x8 vv0 = *(const bf16x8*)(vg0 + kt);
    bf16x8 vv1 = *(const bf16x8*)(vg1 + kt);
    int2 mk0 = *(const int2*)(mrow + kt);
    int2 mk1 = *(const int2*)(mrow + kt + 32);

    __syncthreads();  // previous tile's compute done (WAR on Ks/Vs/Ps)
    *(bf16x8*)&Ks[ko0] = kv0;
    *(bf16x8*)&Ks[ko1] = kv1;
    *(bf16x8*)&Vs[vo0] = vv0;
    *(bf16x8*)&Vs[vo1] = vv1;
    __syncthreads();  // stage visible

#pragma unroll
    for (int g = 0; g < 2; g++) {
      int2 mk = g == 0 ? mk0 : mk1;
      // K-frags shared by both q-groups
      int rowe = (g * 32 + l16) * 72;
      int rowo = (g * 32 + 16 + l16) * 72;
      bf16x8 e0 = *(const bf16x8*)&Ks[rowe + quad * 8];
      bf16x8 e1 = *(const bf16x8*)&Ks[rowe + 32 + quad * 8];
      bf16x8 o0 = *(const bf16x8*)&Ks[rowo + quad * 8];
      bf16x8 o1 = *(const bf16x8*)&Ks[rowo + 32 + quad * 8];
      f32x4 seA = mfma16(qfA1, e1, mfma16(qfA0, e0, zero));
      f32x4 soA = mfma16(qfA1, o1, mfma16(qfA0, o0, zero));
      f32x4 seB = mfma16(qfB1, e1, mfma16(qfB0, e0, zero));
      f32x4 soB = mfma16(qfB1, o1, mfma16(qfB0, o0, zero));
#pragma unroll
      for (int r = 0; r < 4; r++) {
        float pA0 = mk.x ? exp2f(seA[r]) : 0.f;
        float pA1 = mk.y ? exp2f(soA[r]) : 0.f;
        float pB0 = mk.x ? exp2f(seB[r]) : 0.f;
        float pB1 = mk.y ? exp2f(soB[r]) : 0.f;
        l_pA[r] += pA0 + pA1;
        l_pB[r] += pB0 + pB1;
        unsigned pkA = __builtin_amdgcn_perm(__float_as_uint(pA1),
                                             __float_as_uint(pA0), 0x07060302u);
        unsigned pkB = __builtin_amdgcn_perm(__float_as_uint(pB1),
                                             __float_as_uint(pB0), 0x07060302u);
        *(unsigned*)&pw[(quad * 4 + r) * 72 + g * 32 + 2 * l16] = pkA;
        *(unsigned*)&pw[(16 + quad * 4 + r) * 72 + g * 32 + 2 * l16] = pkB;
      }
    }
    bf16x8 pfA0 = *(const bf16x8*)&pw[l16 * 72 + quad * 8];
    bf16x8 pfA1 = *(const bf16x8*)&pw[l16 * 72 + 32 + quad * 8];
    bf16x8 pfB0 = *(const bf16x8*)&pw[(16 + l16) * 72 + quad * 8];
    bf16x8 pfB1 = *(const bf16x8*)&pw[(16 + l16) * 72 + 32 + quad * 8];
#pragma unroll
    for (int c = 0; c < 4; c++) {
      bf16x8 vf0 = *(const bf16x8*)&Vs[(c * 16 + l16) * 72 + quad * 8];
      bf16x8 vf1 = *(const bf16x8*)&Vs[(c * 16 + l16) * 72 + 32 + quad * 8];
      o_accA[c] = mfma16(pfA1, vf1, mfma16(pfA0, vf0, o_accA[c]));
      o_accB[c] = mfma16(pfB1, vf1, mfma16(pfB0, vf0, o_accB[c]));
    }
  }

#pragma unroll
  for (int r = 0; r < 4; r++) {
    float sA = l_pA[r], sB = l_pB[r];
#pragma unroll
    for (int off = 1; off < 16; off <<= 1) {
      sA += __shfl_xor(sA, off);
      sB += __shfl_xor(sB, off);
    }
    float invA = 1.f / sA, invB = 1.f / sB;
    int srowA = qrow0 + quad * 4 + r;
    int srowB = qrow0 + 16 + quad * 4 + r;
#pragma unroll
    for (int c = 0; c < 4; c++) {
      ao[((size_t)(b * S_ + srowA)) * D_ + h * HD_ + c * 16 + l16] =
          f2bf(o_accA[c][r] * invA);
      ao[((size_t)(b * S_ + srowB)) * D_ + h * HD_ + c * 16 + l16] =
          f2bf(o_accB[c][r] * invB);
    }
  }
}

// ---------------- residual (2 partials) + layernorm ----------------
__global__ __launch_bounds__(256) void ln_kernel(
    const float* __restrict__ xa, const float* __restrict__ add0,
    const float* __restrict__ add1,
    const float* __restrict__ g, const float* __restrict__ be,
    float* __restrict__ outf, u16* __restrict__ outb) {
  int row = blockIdx.x;
  int tid = threadIdx.x;
  int lane = tid & 63;
  int wv = tid >> 6;
  const float4 a = *(const float4*)(xa + (size_t)row * D_ + tid * 4);
  const float4 c = *(const float4*)(add0 + (size_t)row * D_ + tid * 4);
  const float4 d = *(const float4*)(add1 + (size_t)row * D_ + tid * 4);
  float v0 = a.x + c.x + d.x, v1 = a.y + c.y + d.y;
  float v2 = a.z + c.z + d.z, v3 = a.w + c.w + d.w;
  float s = v0 + v1 + v2 + v3;
  float sq = v0 * v0 + v1 * v1 + v2 * v2 + v3 * v3;
#pragma unroll
  for (int off = 1; off < 64; off <<= 1) {
    s += __shfl_xor(s, off);
    sq += __shfl_xor(sq, off);
  }
  __shared__ float red[8];
  if (lane == 0) { red[wv] = s; red[4 + wv] = sq; }
  __syncthreads();
  s = red[0] + red[1] + red[2] + red[3];
  sq = red[4] + red[5] + red[6] + red[7];
  float mean = s * (1.f / D_);
  float var = sq * (1.f / D_) - mean * mean;
  float rstd = rsqrtf(var + 1e-5f);
  const float4 gv = *(const float4*)(g + tid * 4);
  const float4 bv = *(const float4*)(be + tid * 4);
  float y0 = (v0 - mean) * rstd * gv.x + bv.x;
  float y1 = (v1 - mean) * rstd * gv.y + bv.y;
  float y2 = (v2 - mean) * rstd * gv.z + bv.z;
  float y3 = (v3 - mean) * rstd * gv.w + bv.w;
  float4 o = {y0, y1, y2, y3};
  *(float4*)(outf + (size_t)row * D_ + tid * 4) = o;
  if (outb) {
    ushort4 ob = {f2bf(y0), f2bf(y1), f2bf(y2), f2bf(y3)};
    *(ushort4*)(outb + (size_t)row * D_ + tid * 4) = ob;
  }
}

extern "C" void kernel_launch(void* const* d_in, const int* in_sizes, int n_in,
                              void* d_out, int out_size, void* d_ws, size_t ws_size,
                              hipStream_t stream) {
  const float* x = (const float*)d_in[0];
  const int* mask = (const int*)d_in[1];
  const float* Wq = (const float*)d_in[2];
  const float* bq = (const float*)d_in[3];
  const float* Wk = (const float*)d_in[4];
  const float* bk = (const float*)d_in[5];
  const float* Wv = (const float*)d_in[6];
  const float* bv = (const float*)d_in[7];
  const float* Wo = (const float*)d_in[8];
  const float* bo = (const float*)d_in[9];
  const float* W1 = (const float*)d_in[10];
  const float* b1 = (const float*)d_in[11];
  const float* W2 = (const float*)d_in[12];
  const float* b2 = (const float*)d_in[13];
  const float* g1 = (const float*)d_in[14];
  const float* be1 = (const float*)d_in[15];
  const float* g2 = (const float*)d_in[16];
  const float* be2 = (const float*)d_in[17];

  const size_t MB = 1ull << 20;
  char* ws = (char*)d_ws;
  u16* wTq = (u16*)(ws + 0 * MB);   // [wTq;wTk;wTv] contiguous = fused QKV BT
  u16* wTk = (u16*)(ws + 2 * MB);
  u16* wTv = (u16*)(ws + 4 * MB);
  u16* wTo = (u16*)(ws + 6 * MB);
  u16* w1T = (u16*)(ws + 8 * MB);   // FF x D
  u16* w2T = (u16*)(ws + 16 * MB);  // D x FF
  u16* xb  = (u16*)(ws + 24 * MB);
  u16* qb  = (u16*)(ws + 32 * MB);
  u16* kb  = (u16*)(ws + 40 * MB);
  u16* vb  = (u16*)(ws + 48 * MB);
  u16* ao  = (u16*)(ws + 56 * MB);
  float* proj = (float*)(ws + 64 * MB);  // 2 halves x 16 MB: 64..96
  float* x1f  = (float*)(ws + 24 * MB);  // reuse xb+qb (dead after attn)
  u16*   x1b  = (u16*)(ws + 40 * MB);    // reuse kb (dead after attn)
  u16*   h1   = (u16*)(ws + 96 * MB);    // 32 MB: 96..128
  float* ffn2 = (float*)(ws + 48 * MB);  // 2 halves x 16 MB: 48..80 (vb/ao/proj0 dead)

  cvt_kernel<<<dim3((B_ * S_ * D_) / 1024), dim3(256), 0, stream>>>(x, xb, B_ * S_ * D_);
  transpose_cvt_kernel<<<dim3(32, 32), dim3(256), 0, stream>>>(Wq, wTq, D_, D_);
  transpose_cvt_kernel<<<dim3(32, 32), dim3(256), 0, stream>>>(Wk, wTk, D_, D_);
  transpose_cvt_kernel<<<dim3(32, 32), dim3(256), 0, stream>>>(Wv, wTv, D_, D_);
  transpose_cvt_kernel<<<dim3(32, 32), dim3(256), 0, stream>>>(Wo, wTo, D_, D_);
  transpose_cvt_kernel<<<dim3(32, 128), dim3(256), 0, stream>>>(W1, w1T, D_, FF_);
  transpose_cvt_kernel<<<dim3(128, 32), dim3(256), 0, stream>>>(W2, w2T, FF_, D_);

  gemm_qkv<<<dim3(32, 24), dim3(256), 0, stream>>>(xb, wTq, bq, bk, bv, qb, kb, vb);

  attn_kernel<<<dim3(S_ / 128, B_ * H_), dim3(256), 0, stream>>>(qb, kb, vb, mask, ao);

  // proj: 128x128 split-K x2 (512 blocks, 2/CU), partials to proj[0],proj[1]
  gemm_bt_sk2<<<dim3(32, 8, 2), dim3(256), 0, stream>>>(ao, wTo, bo, proj, 4096, 1024, 1024, 512);

  ln_kernel<<<dim3(4096), dim3(256), 0, stream>>>(
      x, proj, proj + (size_t)4096 * 1024, g1, be1, x1f, x1b);

  gemm_bt_relu<<<dim3(32, 32), dim3(256), 0, stream>>>(x1b, w1T, b1, h1, 4096, 4096, 1024);

  // ffn2: split-K x2 over K=4096, partials to ffn2[0], ffn2[1]
  gemm_bt_sk2<<<dim3(32, 8, 2), dim3(256), 0, stream>>>(h1, w2T, b2, ffn2, 4096, 1024, 4096, 2048);

  ln_kernel<<<dim3(4096), dim3(256), 0, stream>>>(
      x1f, ffn2, ffn2 + (size_t)4096 * 1024, g2, be2, (float*)d_out, (u16*)nullptr);
}

// Round 7
// 406.064 us; speedup vs baseline: 1.0053x; 1.0053x over previous
//
#include <hip/hip_runtime.h>
#include <stdint.h>
#include <stddef.h>

#define B_ 2
#define S_ 2048
#define D_ 1024
#define H_ 16
#define HD_ 64
#define FF_ 4096

typedef unsigned short u16;
typedef __attribute__((ext_vector_type(8))) short bf16x8;
typedef __attribute__((ext_vector_type(4))) float f32x4;

__device__ __forceinline__ u16 f2bf(float f) {
  unsigned u = __float_as_uint(f);
  u += 0x7fffu + ((u >> 16) & 1u);
  return (u16)(u >> 16);
}

__device__ __forceinline__ f32x4 mfma16(bf16x8 a, bf16x8 b, f32x4 c) {
  return __builtin_amdgcn_mfma_f32_16x16x32_bf16(a, b, c, 0, 0, 0);
}

__device__ __forceinline__ void gload16(const void* g, void* l) {
  __builtin_amdgcn_global_load_lds(
      (const __attribute__((address_space(1))) void*)g,
      (__attribute__((address_space(3))) void*)l, 16, 0, 0);
}

// XCD-aware block swizzle (bijective when gridDim.x % 8 == 0).
__device__ __forceinline__ void swizzle_mn(int& mt, int& nt) {
  int gm = gridDim.x;
  if ((gm & 7) == 0) {
    int bid = blockIdx.y * gm + blockIdx.x;
    int mper = gm >> 3;
    int xcd = bid & 7, idx = bid >> 3;
    mt = xcd * mper + (idx % mper);
    nt = idx / mper;
  } else {
    mt = blockIdx.x;
    nt = blockIdx.y;
  }
}

// ---------------- elementwise fp32 -> bf16 ----------------
__global__ __launch_bounds__(256) void cvt_kernel(const float* __restrict__ src,
                                                  u16* __restrict__ dst, int n) {
  int i = (blockIdx.x * 256 + threadIdx.x) * 4;
  if (i >= n) return;
  float4 v = *(const float4*)(src + i);
  ushort4 o = { f2bf(v.x), f2bf(v.y), f2bf(v.z), f2bf(v.w) };
  *(ushort4*)(dst + i) = o;
}

// ---------------- transpose + convert: W (K x N) fp32 -> WT (N x K) bf16 ----
__global__ __launch_bounds__(256) void transpose_cvt_kernel(
    const float* __restrict__ W, u16* __restrict__ WT, int K, int N) {
  __shared__ u16 t[32][33];
  int k0 = blockIdx.x * 32;
  int n0 = blockIdx.y * 32;
  int tid = threadIdx.x;
  int r = tid >> 3;
  int c = (tid & 7) << 2;
  float4 v = *(const float4*)(W + (size_t)(k0 + r) * N + n0 + c);
  t[r][c + 0] = f2bf(v.x); t[r][c + 1] = f2bf(v.y);
  t[r][c + 2] = f2bf(v.z); t[r][c + 3] = f2bf(v.w);
  __syncthreads();
  ushort4 o;
  o.x = t[c + 0][r]; o.y = t[c + 1][r]; o.z = t[c + 2][r]; o.w = t[c + 3][r];
  *(ushort4*)(WT + (size_t)(n0 + r) * K + k0 + c) = o;
}

// Four D x D transposes in one launch (z selects weight).
__global__ __launch_bounds__(256) void transpose_cvt4_kernel(
    const float* __restrict__ s0, const float* __restrict__ s1,
    const float* __restrict__ s2, const float* __restrict__ s3,
    u16* __restrict__ d0, u16* __restrict__ d1,
    u16* __restrict__ d2, u16* __restrict__ d3) {
  __shared__ u16 t[32][33];
  int z = blockIdx.z;
  const float* W = z == 0 ? s0 : (z == 1 ? s1 : (z == 2 ? s2 : s3));
  u16* WT = z == 0 ? d0 : (z == 1 ? d1 : (z == 2 ? d2 : d3));
  int k0 = blockIdx.x * 32;
  int n0 = blockIdx.y * 32;
  int tid = threadIdx.x;
  int r = tid >> 3;
  int c = (tid & 7) << 2;
  float4 v = *(const float4*)(W + (size_t)(k0 + r) * D_ + n0 + c);
  t[r][c + 0] = f2bf(v.x); t[r][c + 1] = f2bf(v.y);
  t[r][c + 2] = f2bf(v.z); t[r][c + 3] = f2bf(v.w);
  __syncthreads();
  ushort4 o;
  o.x = t[c + 0][r]; o.y = t[c + 1][r]; o.z = t[c + 2][r]; o.w = t[c + 3][r];
  *(ushort4*)(WT + (size_t)(n0 + r) * D_ + k0 + c) = o;
}

// ---------------- GEMM 128x128, out bf16 + relu (+bias)  [ffn1] ------------
__global__ __launch_bounds__(256) void gemm_bt_relu(
    const u16* __restrict__ A, const u16* __restrict__ BT,
    const float* __restrict__ bias, u16* __restrict__ outp,
    int M, int N, int K) {
  __shared__ __align__(16) u16 As[128 * 32];
  __shared__ __align__(16) u16 Bs[128 * 32];
  int tid = threadIdx.x;
  int lane = tid & 63;
  int wave = tid >> 6;
  int quad = lane >> 4;
  int l16 = lane & 15;
  int mt, nt;
  swizzle_mn(mt, nt);
  int m0 = mt * 128;
  int n0 = nt * 128;
  int wm = (wave >> 1) * 64;
  int wn = (wave & 1) * 64;

  f32x4 zero = {0.f, 0.f, 0.f, 0.f};
  f32x4 acc[4][4];
#pragma unroll
  for (int i = 0; i < 4; i++)
#pragma unroll
    for (int j = 0; j < 4; j++) acc[i][j] = zero;

  int c0 = tid, c1 = tid + 256;
  const u16* ga0 = A + (size_t)(m0 + (c0 >> 2)) * K + (c0 & 3) * 8;
  const u16* ga1 = A + (size_t)(m0 + (c1 >> 2)) * K + (c1 & 3) * 8;
  const u16* gb0 = BT + (size_t)(n0 + (c0 >> 2)) * K + (c0 & 3) * 8;
  const u16* gb1 = BT + (size_t)(n0 + (c1 >> 2)) * K + (c1 & 3) * 8;

  for (int k0 = 0; k0 < K; k0 += 32) {
    gload16(ga0 + k0, &As[c0 * 8]);
    gload16(ga1 + k0, &As[c1 * 8]);
    gload16(gb0 + k0, &Bs[c0 * 8]);
    gload16(gb1 + k0, &Bs[c1 * 8]);
    __syncthreads();
    bf16x8 af[4], bfr[4];
#pragma unroll
    for (int i = 0; i < 4; i++)
      af[i] = *(const bf16x8*)&As[(wm + i * 16 + l16) * 32 + quad * 8];
#pragma unroll
    for (int j = 0; j < 4; j++)
      bfr[j] = *(const bf16x8*)&Bs[(wn + j * 16 + l16) * 32 + quad * 8];
#pragma unroll
    for (int i = 0; i < 4; i++)
#pragma unroll
      for (int j = 0; j < 4; j++)
        acc[i][j] = mfma16(af[i], bfr[j], acc[i][j]);
    __syncthreads();
  }

#pragma unroll
  for (int j = 0; j < 4; j++) {
    int gcol = n0 + wn + j * 16 + l16;
    float bv = bias[gcol];
#pragma unroll
    for (int i = 0; i < 4; i++) {
#pragma unroll
      for (int r = 0; r < 4; r++) {
        int grow = m0 + wm + i * 16 + quad * 4 + r;
        float val = acc[i][j][r] + bv;
        outp[(size_t)grow * N + gcol] = f2bf(val > 0.f ? val : 0.f);
      }
    }
  }
}

// ---------------- GEMM 128x128 split-K (up to 4), separate fp32 outputs ----
// z covers K-range [z*Kc,(z+1)*Kc); writes the z-th output pointer. Bias z=0.
__global__ __launch_bounds__(256) void gemm_bt_sk4(
    const u16* __restrict__ A, const u16* __restrict__ BT,
    const float* __restrict__ bias,
    float* __restrict__ o0, float* __restrict__ o1,
    float* __restrict__ o2, float* __restrict__ o3,
    int M, int N, int K, int Kc) {
  __shared__ __align__(16) u16 As[128 * 32];
  __shared__ __align__(16) u16 Bs[128 * 32];
  int tid = threadIdx.x;
  int lane = tid & 63;
  int wave = tid >> 6;
  int quad = lane >> 4;
  int l16 = lane & 15;
  int mt, nt;
  swizzle_mn(mt, nt);
  int m0 = mt * 128;
  int n0 = nt * 128;
  int z = blockIdx.z;
  int kb = z * Kc;
  int wm = (wave >> 1) * 64;
  int wn = (wave & 1) * 64;

  f32x4 zero = {0.f, 0.f, 0.f, 0.f};
  f32x4 acc[4][4];
#pragma unroll
  for (int i = 0; i < 4; i++)
#pragma unroll
    for (int j = 0; j < 4; j++) acc[i][j] = zero;

  int c0 = tid, c1 = tid + 256;
  const u16* ga0 = A + (size_t)(m0 + (c0 >> 2)) * K + (c0 & 3) * 8 + kb;
  const u16* ga1 = A + (size_t)(m0 + (c1 >> 2)) * K + (c1 & 3) * 8 + kb;
  const u16* gb0 = BT + (size_t)(n0 + (c0 >> 2)) * K + (c0 & 3) * 8 + kb;
  const u16* gb1 = BT + (size_t)(n0 + (c1 >> 2)) * K + (c1 & 3) * 8 + kb;

  for (int k0 = 0; k0 < Kc; k0 += 32) {
    gload16(ga0 + k0, &As[c0 * 8]);
    gload16(ga1 + k0, &As[c1 * 8]);
    gload16(gb0 + k0, &Bs[c0 * 8]);
    gload16(gb1 + k0, &Bs[c1 * 8]);
    __syncthreads();
    bf16x8 af[4], bfr[4];
#pragma unroll
    for (int i = 0; i < 4; i++)
      af[i] = *(const bf16x8*)&As[(wm + i * 16 + l16) * 32 + quad * 8];
#pragma unroll
    for (int j = 0; j < 4; j++)
      bfr[j] = *(const bf16x8*)&Bs[(wn + j * 16 + l16) * 32 + quad * 8];
#pragma unroll
    for (int i = 0; i < 4; i++)
#pragma unroll
      for (int j = 0; j < 4; j++)
        acc[i][j] = mfma16(af[i], bfr[j], acc[i][j]);
    __syncthreads();
  }

  float* outz = z == 0 ? o0 : (z == 1 ? o1 : (z == 2 ? o2 : o3));
  float biasmul = (z == 0) ? 1.f : 0.f;
#pragma unroll
  for (int j = 0; j < 4; j++) {
    int gcol = n0 + wn + j * 16 + l16;
    float bv = bias[gcol] * biasmul;
#pragma unroll
    for (int i = 0; i < 4; i++) {
#pragma unroll
      for (int r = 0; r < 4; r++) {
        int grow = m0 + wm + i * 16 + quad * 4 + r;
        outz[(size_t)grow * N + gcol] = acc[i][j][r] + bv;
      }
    }
  }
}

// ---------------- fused QKV GEMM (q pre-scaled by 1/sqrt(HD)*log2e) --------
__global__ __launch_bounds__(256) void gemm_qkv(
    const u16* __restrict__ A, const u16* __restrict__ BT,
    const float* __restrict__ bq, const float* __restrict__ bk,
    const float* __restrict__ bvp,
    u16* __restrict__ qb, u16* __restrict__ kb, u16* __restrict__ vb) {
  const int K = 1024;
  __shared__ __align__(16) u16 As[128 * 32];
  __shared__ __align__(16) u16 Bs[128 * 32];
  int tid = threadIdx.x;
  int lane = tid & 63;
  int wave = tid >> 6;
  int quad = lane >> 4;
  int l16 = lane & 15;
  int mt, nt;
  swizzle_mn(mt, nt);
  int m0 = mt * 128;
  int n0 = nt * 128;
  int wm = (wave >> 1) * 64;
  int wn = (wave & 1) * 64;

  f32x4 zero = {0.f, 0.f, 0.f, 0.f};
  f32x4 acc[4][4];
#pragma unroll
  for (int i = 0; i < 4; i++)
#pragma unroll
    for (int j = 0; j < 4; j++) acc[i][j] = zero;

  int c0 = tid, c1 = tid + 256;
  const u16* ga0 = A + (size_t)(m0 + (c0 >> 2)) * K + (c0 & 3) * 8;
  const u16* ga1 = A + (size_t)(m0 + (c1 >> 2)) * K + (c1 & 3) * 8;
  const u16* gb0 = BT + (size_t)(n0 + (c0 >> 2)) * K + (c0 & 3) * 8;
  const u16* gb1 = BT + (size_t)(n0 + (c1 >> 2)) * K + (c1 & 3) * 8;

  for (int k0 = 0; k0 < K; k0 += 32) {
    gload16(ga0 + k0, &As[c0 * 8]);
    gload16(ga1 + k0, &As[c1 * 8]);
    gload16(gb0 + k0, &Bs[c0 * 8]);
    gload16(gb1 + k0, &Bs[c1 * 8]);
    __syncthreads();
    bf16x8 af[4], bfr[4];
#pragma unroll
    for (int i = 0; i < 4; i++)
      af[i] = *(const bf16x8*)&As[(wm + i * 16 + l16) * 32 + quad * 8];
#pragma unroll
    for (int j = 0; j < 4; j++)
      bfr[j] = *(const bf16x8*)&Bs[(wn + j * 16 + l16) * 32 + quad * 8];
#pragma unroll
    for (int i = 0; i < 4; i++)
#pragma unroll
      for (int j = 0; j < 4; j++)
        acc[i][j] = mfma16(af[i], bfr[j], acc[i][j]);
    __syncthreads();
  }

  int region = n0 >> 10;
  const float* bias = region == 0 ? bq : (region == 1 ? bk : bvp);
  u16* outp = region == 0 ? qb : (region == 1 ? kb : vb);
  float scale = region == 0 ? 0.125f * 1.4426950408889634f : 1.f;

#pragma unroll
  for (int j = 0; j < 4; j++) {
    int gcol = (n0 & 1023) + wn + j * 16 + l16;
    float bv = bias[gcol];
    int h = gcol >> 6, hd = gcol & 63;
#pragma unroll
    for (int i = 0; i < 4; i++) {
#pragma unroll
      for (int r = 0; r < 4; r++) {
        int grow = m0 + wm + i * 16 + quad * 4 + r;
        float val = (acc[i][j][r] + bv) * scale;
        int b = grow >> 11, s = grow & 2047;
        if (region < 2) {
          outp[(((size_t)(b * H_ + h)) * S_ + s) * HD_ + hd] = f2bf(val);
        } else {
          outp[(((size_t)(b * H_ + h)) * HD_ + hd) * S_ + s] = f2bf(val);
        }
      }
    }
  }
}

// ---------------- flash attention: MQ=32/wave, double-buffered K/V ---------
// ONE __syncthreads per 64-key tile: stage tile t+1 into the alternate LDS
// buffer while computing tile t. Ps is wave-private (no barrier needed).
// K staged row-permuted (even keys -> rows 0..15, odd -> 16..31 per 32-group)
// so P-writes are packed b32. Q pre-scaled at projection (p = exp2(s)).
__global__ __launch_bounds__(256, 2) void attn_kernel(
    const u16* __restrict__ q, const u16* __restrict__ k,
    const u16* __restrict__ vt, const int* __restrict__ mask,
    u16* __restrict__ ao) {
  __shared__ __align__(16) u16 Ks[2][64 * 72];
  __shared__ __align__(16) u16 Vs[2][64 * 72];
  __shared__ __align__(16) u16 Ps[4][32 * 72];
  int tid = threadIdx.x;
  int lane = tid & 63;
  int wave = tid >> 6;
  int quad = lane >> 4;
  int l16 = lane & 15;
  int bh = blockIdx.y;
  int b = bh >> 4;
  int h = bh & 15;
  int qrow0 = blockIdx.x * 128 + wave * 32;

  const u16* qh = q + (size_t)bh * S_ * HD_;
  const u16* kh = k + (size_t)bh * S_ * HD_;
  const u16* vh = vt + (size_t)bh * HD_ * S_;

  bf16x8 qfA0 = *(const bf16x8*)(qh + (size_t)(qrow0 + l16) * HD_ + quad * 8);
  bf16x8 qfA1 = *(const bf16x8*)(qh + (size_t)(qrow0 + l16) * HD_ + 32 + quad * 8);
  bf16x8 qfB0 = *(const bf16x8*)(qh + (size_t)(qrow0 + 16 + l16) * HD_ + quad * 8);
  bf16x8 qfB1 = *(const bf16x8*)(qh + (size_t)(qrow0 + 16 + l16) * HD_ + 32 + quad * 8);

  int sr = tid >> 3, sc = tid & 7;
  const u16* kg0 = kh + sr * HD_ + sc * 8;
  const u16* kg1 = kh + (sr + 32) * HD_ + sc * 8;
  const u16* vg0 = vh + (size_t)sr * S_ + sc * 8;
  const u16* vg1 = vh + (size_t)(sr + 32) * S_ + sc * 8;
  int kr0 = (sr & 1) * 16 + (sr >> 1);   // permuted row for key sr
  int ko0 = kr0 * 72 + sc * 8;
  int ko1 = (32 + kr0) * 72 + sc * 8;
  int vo0 = sr * 72 + sc * 8;
  int vo1 = (sr + 32) * 72 + sc * 8;
  const int* mrow = mask + b * S_ + 2 * l16;

  float l_pA[4] = {0.f, 0.f, 0.f, 0.f};
  float l_pB[4] = {0.f, 0.f, 0.f, 0.f};
  f32x4 zero = {0.f, 0.f, 0.f, 0.f};
  f32x4 o_accA[4], o_accB[4];
#pragma unroll
  for (int c = 0; c < 4; c++) { o_accA[c] = zero; o_accB[c] = zero; }

  u16* pw = &Ps[wave][0];

  // prologue: stage tile 0 into buf 0, prefetch tile 1 into regs
  bf16x8 kv0 = *(const bf16x8*)(kg0);
  bf16x8 kv1 = *(const bf16x8*)(kg1);
  bf16x8 vv0 = *(const bf16x8*)(vg0);
  bf16x8 vv1 = *(const bf16x8*)(vg1);
  *(bf16x8*)&Ks[0][ko0] = kv0;
  *(bf16x8*)&Ks[0][ko1] = kv1;
  *(bf16x8*)&Vs[0][vo0] = vv0;
  *(bf16x8*)&Vs[0][vo1] = vv1;
  kv0 = *(const bf16x8*)(kg0 + (size_t)64 * HD_);
  kv1 = *(const bf16x8*)(kg1 + (size_t)64 * HD_);
  vv0 = *(const bf16x8*)(vg0 + 64);
  vv1 = *(const bf16x8*)(vg1 + 64);

  int cur = 0;
  for (int kt = 0; kt < S_; kt += 64) {
    int2 mk0 = *(const int2*)(mrow + kt);
    int2 mk1 = *(const int2*)(mrow + kt + 32);

    __syncthreads();  // buf[cur] (tile kt) fully staged; prev compute done
    if (kt + 64 < S_) {
      int alt = cur ^ 1;
      *(bf16x8*)&Ks[alt][ko0] = kv0;
      *(bf16x8*)&Ks[alt][ko1] = kv1;
      *(bf16x8*)&Vs[alt][vo0] = vv0;
      *(bf16x8*)&Vs[alt][vo1] = vv1;
      int nk = (kt + 128) & (S_ - 1);  // wrap: harmless dummy on tail
      kv0 = *(const bf16x8*)(kg0 + (size_t)nk * HD_);
      kv1 = *(const bf16x8*)(kg1 + (size_t)nk * HD_);
      vv0 = *(const bf16x8*)(vg0 + nk);
      vv1 = *(const bf16x8*)(vg1 + nk);
    }

    const u16* ksb = &Ks[cur][0];
    const u16* vsb = &Vs[cur][0];
#pragma unroll
    for (int g = 0; g < 2; g++) {
      int2 mk = g == 0 ? mk0 : mk1;
      int rowe = (g * 32 + l16) * 72;
      int rowo = (g * 32 + 16 + l16) * 72;
      bf16x8 e0 = *(const bf16x8*)&ksb[rowe + quad * 8];
      bf16x8 e1 = *(const bf16x8*)&ksb[rowe + 32 + quad * 8];
      bf16x8 o0 = *(const bf16x8*)&ksb[rowo + quad * 8];
      bf16x8 o1 = *(const bf16x8*)&ksb[rowo + 32 + quad * 8];
      f32x4 seA = mfma16(qfA1, e1, mfma16(qfA0, e0, zero));
      f32x4 soA = mfma16(qfA1, o1, mfma16(qfA0, o0, zero));
      f32x4 seB = mfma16(qfB1, e1, mfma16(qfB0, e0, zero));
      f32x4 soB = mfma16(qfB1, o1, mfma16(qfB0, o0, zero));
#pragma unroll
      for (int r = 0; r < 4; r++) {
        float pA0 = mk.x ? exp2f(seA[r]) : 0.f;
        float pA1 = mk.y ? exp2f(soA[r]) : 0.f;
        float pB0 = mk.x ? exp2f(seB[r]) : 0.f;
        float pB1 = mk.y ? exp2f(soB[r]) : 0.f;
        l_pA[r] += pA0 + pA1;
        l_pB[r] += pB0 + pB1;
        unsigned pkA = __builtin_amdgcn_perm(__float_as_uint(pA1),
                                             __float_as_uint(pA0), 0x07060302u);
        unsigned pkB = __builtin_amdgcn_perm(__float_as_uint(pB1),
                                             __float_as_uint(pB0), 0x07060302u);
        *(unsigned*)&pw[(quad * 4 + r) * 72 + g * 32 + 2 * l16] = pkA;
        *(unsigned*)&pw[(16 + quad * 4 + r) * 72 + g * 32 + 2 * l16] = pkB;
      }
    }
    bf16x8 pfA0 = *(const bf16x8*)&pw[l16 * 72 + quad * 8];
    bf16x8 pfA1 = *(const bf16x8*)&pw[l16 * 72 + 32 + quad * 8];
    bf16x8 pfB0 = *(const bf16x8*)&pw[(16 + l16) * 72 + quad * 8];
    bf16x8 pfB1 = *(const bf16x8*)&pw[(16 + l16) * 72 + 32 + quad * 8];
#pragma unroll
    for (int c = 0; c < 4; c++) {
      bf16x8 vf0 = *(const bf16x8*)&vsb[(c * 16 + l16) * 72 + quad * 8];
      bf16x8 vf1 = *(const bf16x8*)&vsb[(c * 16 + l16) * 72 + 32 + quad * 8];
      o_accA[c] = mfma16(pfA1, vf1, mfma16(pfA0, vf0, o_accA[c]));
      o_accB[c] = mfma16(pfB1, vf1, mfma16(pfB0, vf0, o_accB[c]));
    }
    cur ^= 1;
  }

#pragma unroll
  for (int r = 0; r < 4; r++) {
    float sA = l_pA[r], sB = l_pB[r];
#pragma unroll
    for (int off = 1; off < 16; off <<= 1) {
      sA += __shfl_xor(sA, off);
      sB += __shfl_xor(sB, off);
    }
    float invA = 1.f / sA, invB = 1.f / sB;
    int srowA = qrow0 + quad * 4 + r;
    int srowB = qrow0 + 16 + quad * 4 + r;
#pragma unroll
    for (int c = 0; c < 4; c++) {
      ao[((size_t)(b * S_ + srowA)) * D_ + h * HD_ + c * 16 + l16] =
          f2bf(o_accA[c][r] * invA);
      ao[((size_t)(b * S_ + srowB)) * D_ + h * HD_ + c * 16 + l16] =
          f2bf(o_accB[c][r] * invB);
    }
  }
}

// ---------------- residual (2 partials) + layernorm ----------------
__global__ __launch_bounds__(256) void ln_kernel(
    const float* __restrict__ xa, const float* __restrict__ add0,
    const float* __restrict__ add1,
    const float* __restrict__ g, const float* __restrict__ be,
    float* __restrict__ outf, u16* __restrict__ outb) {
  int row = blockIdx.x;
  int tid = threadIdx.x;
  int lane = tid & 63;
  int wv = tid >> 6;
  const float4 a = *(const float4*)(xa + (size_t)row * D_ + tid * 4);
  const float4 c = *(const float4*)(add0 + (size_t)row * D_ + tid * 4);
  const float4 d = *(const float4*)(add1 + (size_t)row * D_ + tid * 4);
  float v0 = a.x + c.x + d.x, v1 = a.y + c.y + d.y;
  float v2 = a.z + c.z + d.z, v3 = a.w + c.w + d.w;
  float s = v0 + v1 + v2 + v3;
  float sq = v0 * v0 + v1 * v1 + v2 * v2 + v3 * v3;
#pragma unroll
  for (int off = 1; off < 64; off <<= 1) {
    s += __shfl_xor(s, off);
    sq += __shfl_xor(sq, off);
  }
  __shared__ float red[8];
  if (lane == 0) { red[wv] = s; red[4 + wv] = sq; }
  __syncthreads();
  s = red[0] + red[1] + red[2] + red[3];
  sq = red[4] + red[5] + red[6] + red[7];
  float mean = s * (1.f / D_);
  float var = sq * (1.f / D_) - mean * mean;
  float rstd = rsqrtf(var + 1e-5f);
  const float4 gv = *(const float4*)(g + tid * 4);
  const float4 bv = *(const float4*)(be + tid * 4);
  float y0 = (v0 - mean) * rstd * gv.x + bv.x;
  float y1 = (v1 - mean) * rstd * gv.y + bv.y;
  float y2 = (v2 - mean) * rstd * gv.z + bv.z;
  float y3 = (v3 - mean) * rstd * gv.w + bv.w;
  float4 o = {y0, y1, y2, y3};
  *(float4*)(outf + (size_t)row * D_ + tid * 4) = o;
  if (outb) {
    ushort4 ob = {f2bf(y0), f2bf(y1), f2bf(y2), f2bf(y3)};
    *(ushort4*)(outb + (size_t)row * D_ + tid * 4) = ob;
  }
}

// ---------------- residual (4 partials) + layernorm ----------------
__global__ __launch_bounds__(256) void ln4_kernel(
    const float* __restrict__ xa,
    const float* __restrict__ a0, const float* __restrict__ a1,
    const float* __restrict__ a2, const float* __restrict__ a3,
    const float* __restrict__ g, const float* __restrict__ be,
    float* __restrict__ outf, u16* __restrict__ outb) {
  int row = blockIdx.x;
  int tid = threadIdx.x;
  int lane = tid & 63;
  int wv = tid >> 6;
  size_t off0 = (size_t)row * D_ + tid * 4;
  const float4 a = *(const float4*)(xa + off0);
  const float4 c0 = *(const float4*)(a0 + off0);
  const float4 c1 = *(const float4*)(a1 + off0);
  const float4 c2 = *(const float4*)(a2 + off0);
  const float4 c3 = *(const float4*)(a3 + off0);
  float v0 = a.x + (c0.x + c1.x) + (c2.x + c3.x);
  float v1 = a.y + (c0.y + c1.y) + (c2.y + c3.y);
  float v2 = a.z + (c0.z + c1.z) + (c2.z + c3.z);
  float v3 = a.w + (c0.w + c1.w) + (c2.w + c3.w);
  float s = v0 + v1 + v2 + v3;
  float sq = v0 * v0 + v1 * v1 + v2 * v2 + v3 * v3;
#pragma unroll
  for (int off = 1; off < 64; off <<= 1) {
    s += __shfl_xor(s, off);
    sq += __shfl_xor(sq, off);
  }
  __shared__ float red[8];
  if (lane == 0) { red[wv] = s; red[4 + wv] = sq; }
  __syncthreads();
  s = red[0] + red[1] + red[2] + red[3];
  sq = red[4] + red[5] + red[6] + red[7];
  float mean = s * (1.f / D_);
  float var = sq * (1.f / D_) - mean * mean;
  float rstd = rsqrtf(var + 1e-5f);
  const float4 gv = *(const float4*)(g + tid * 4);
  const float4 bv = *(const float4*)(be + tid * 4);
  float y0 = (v0 - mean) * rstd * gv.x + bv.x;
  float y1 = (v1 - mean) * rstd * gv.y + bv.y;
  float y2 = (v2 - mean) * rstd * gv.z + bv.z;
  float y3 = (v3 - mean) * rstd * gv.w + bv.w;
  float4 o = {y0, y1, y2, y3};
  *(float4*)(outf + off0) = o;
  if (outb) {
    ushort4 ob = {f2bf(y0), f2bf(y1), f2bf(y2), f2bf(y3)};
    *(ushort4*)(outb + off0) = ob;
  }
}

extern "C" void kernel_launch(void* const* d_in, const int* in_sizes, int n_in,
                              void* d_out, int out_size, void* d_ws, size_t ws_size,
                              hipStream_t stream) {
  const float* x = (const float*)d_in[0];
  const int* mask = (const int*)d_in[1];
  const float* Wq = (const float*)d_in[2];
  const float* bq = (const float*)d_in[3];
  const float* Wk = (const float*)d_in[4];
  const float* bk = (const float*)d_in[5];
  const float* Wv = (const float*)d_in[6];
  const float* bv = (const float*)d_in[7];
  const float* Wo = (const float*)d_in[8];
  const float* bo = (const float*)d_in[9];
  const float* W1 = (const float*)d_in[10];
  const float* b1 = (const float*)d_in[11];
  const float* W2 = (const float*)d_in[12];
  const float* b2 = (const float*)d_in[13];
  const float* g1 = (const float*)d_in[14];
  const float* be1 = (const float*)d_in[15];
  const float* g2 = (const float*)d_in[16];
  const float* be2 = (const float*)d_in[17];

  const size_t MB = 1ull << 20;
  char* ws = (char*)d_ws;
  u16* wTq = (u16*)(ws + 0 * MB);   // [wTq;wTk;wTv] contiguous = fused QKV BT
  u16* wTk = (u16*)(ws + 2 * MB);
  u16* wTv = (u16*)(ws + 4 * MB);
  u16* wTo = (u16*)(ws + 6 * MB);
  u16* w1T = (u16*)(ws + 8 * MB);   // FF x D
  u16* w2T = (u16*)(ws + 16 * MB);  // D x FF (live through ffn2)
  u16* xb  = (u16*)(ws + 24 * MB);
  u16* qb  = (u16*)(ws + 32 * MB);
  u16* kb  = (u16*)(ws + 40 * MB);
  u16* vb  = (u16*)(ws + 48 * MB);
  u16* ao  = (u16*)(ws + 56 * MB);
  float* p0 = (float*)(ws + 64 * MB);    // proj partials (sk2): 64..96
  float* p1 = (float*)(ws + 80 * MB);
  float* x1f = (float*)(ws + 24 * MB);   // reuse xb+qb (dead after attn)
  u16*   x1b = (u16*)(ws + 40 * MB);     // reuse kb (dead after attn)
  u16*   h1  = (u16*)(ws + 48 * MB);     // 48..80 (vb/ao/p0 dead after LN1)
  float* f0 = (float*)(ws + 80 * MB);    // ffn2 partials (sk4)
  float* f1 = (float*)(ws + 96 * MB);
  float* f2 = (float*)(ws + 112 * MB);
  float* f3 = (float*)(ws + 0 * MB);     // weights 0..16 dead by ffn2 time

  cvt_kernel<<<dim3((B_ * S_ * D_) / 1024), dim3(256), 0, stream>>>(x, xb, B_ * S_ * D_);
  transpose_cvt4_kernel<<<dim3(32, 32, 4), dim3(256), 0, stream>>>(
      Wq, Wk, Wv, Wo, wTq, wTk, wTv, wTo);
  transpose_cvt_kernel<<<dim3(32, 128), dim3(256), 0, stream>>>(W1, w1T, D_, FF_);
  transpose_cvt_kernel<<<dim3(128, 32), dim3(256), 0, stream>>>(W2, w2T, FF_, D_);

  gemm_qkv<<<dim3(32, 24), dim3(256), 0, stream>>>(xb, wTq, bq, bk, bv, qb, kb, vb);

  attn_kernel<<<dim3(S_ / 128, B_ * H_), dim3(256), 0, stream>>>(qb, kb, vb, mask, ao);

  // proj: split-K x2 (512 blocks), partials p0,p1
  gemm_bt_sk4<<<dim3(32, 8, 2), dim3(256), 0, stream>>>(
      ao, wTo, bo, p0, p1, p0, p0, 4096, 1024, 1024, 512);

  ln_kernel<<<dim3(4096), dim3(256), 0, stream>>>(x, p0, p1, g1, be1, x1f, x1b);

  gemm_bt_relu<<<dim3(32, 32), dim3(256), 0, stream>>>(x1b, w1T, b1, h1, 4096, 4096, 1024);

  // ffn2: split-K x4 (1024 blocks, 4/CU), partials f0..f3
  gemm_bt_sk4<<<dim3(32, 8, 4), dim3(256), 0, stream>>>(
      h1, w2T, b2, f0, f1, f2, f3, 4096, 1024, 4096, 1024);

  ln4_kernel<<<dim3(4096), dim3(256), 0, stream>>>(
      x1f, f0, f1, f2, f3, g2, be2, (float*)d_out, (u16*)nullptr);
}

// Round 8
// 370.178 us; speedup vs baseline: 1.1028x; 1.0969x over previous
//
#include <hip/hip_runtime.h>
#include <stdint.h>
#include <stddef.h>

#define B_ 2
#define S_ 2048
#define D_ 1024
#define H_ 16
#define HD_ 64
#define FF_ 4096

typedef unsigned short u16;
typedef __attribute__((ext_vector_type(8))) short bf16x8;
typedef __attribute__((ext_vector_type(4))) float f32x4;

__device__ __forceinline__ u16 f2bf(float f) {
  unsigned u = __float_as_uint(f);
  u += 0x7fffu + ((u >> 16) & 1u);
  return (u16)(u >> 16);
}

__device__ __forceinline__ f32x4 mfma16(bf16x8 a, bf16x8 b, f32x4 c) {
  return __builtin_amdgcn_mfma_f32_16x16x32_bf16(a, b, c, 0, 0, 0);
}

__device__ __forceinline__ void gload16(const void* g, void* l) {
  __builtin_amdgcn_global_load_lds(
      (const __attribute__((address_space(1))) void*)g,
      (__attribute__((address_space(3))) void*)l, 16, 0, 0);
}

// XCD-aware block swizzle (bijective when gridDim.x % 8 == 0).
__device__ __forceinline__ void swizzle_mn(int& mt, int& nt) {
  int gm = gridDim.x;
  if ((gm & 7) == 0) {
    int bid = blockIdx.y * gm + blockIdx.x;
    int mper = gm >> 3;
    int xcd = bid & 7, idx = bid >> 3;
    mt = xcd * mper + (idx % mper);
    nt = idx / mper;
  } else {
    mt = blockIdx.x;
    nt = blockIdx.y;
  }
}

// ---------------- fused prep: x cvt + all weight transposes ----------------
// linear grid, bid-decoded:
//   [0,4096)      W1 transpose tiles (K=1024 x N=4096)
//   [4096,8192)   W2 transpose tiles (K=4096 x N=1024)
//   [8192,12288)  x fp32->bf16 (4096 blocks x 1024 elems)
//   [12288,16384) 4 x DxD transposes (Wq,Wk,Wv,Wo)
__global__ __launch_bounds__(256) void prep_kernel(
    const float* __restrict__ x, u16* __restrict__ xb,
    const float* __restrict__ W1, u16* __restrict__ w1T,
    const float* __restrict__ W2, u16* __restrict__ w2T,
    const float* __restrict__ Wq, const float* __restrict__ Wk,
    const float* __restrict__ Wv, const float* __restrict__ Wo,
    u16* __restrict__ wTq, u16* __restrict__ wTk,
    u16* __restrict__ wTv, u16* __restrict__ wTo) {
  int bid = blockIdx.x;
  int tid = threadIdx.x;
  if (bid >= 8192 && bid < 12288) {  // cvt path (no barrier)
    int i = (bid - 8192) * 1024 + tid * 4;
    float4 v = *(const float4*)(x + i);
    ushort4 o = { f2bf(v.x), f2bf(v.y), f2bf(v.z), f2bf(v.w) };
    *(ushort4*)(xb + i) = o;
    return;
  }
  const float* W;
  u16* WT;
  int K, N, k0, n0;
  if (bid < 4096) {  // W1
    W = W1; WT = w1T; K = 1024; N = 4096;
    k0 = (bid & 31) * 32; n0 = (bid >> 5) * 32;
  } else if (bid < 8192) {  // W2
    int b2 = bid - 4096;
    W = W2; WT = w2T; K = 4096; N = 1024;
    k0 = (b2 >> 5) * 32; n0 = (b2 & 31) * 32;
  } else {  // 4 x DxD
    int t = bid - 12288;
    int z = t >> 10, r = t & 1023;
    W = z == 0 ? Wq : (z == 1 ? Wk : (z == 2 ? Wv : Wo));
    WT = z == 0 ? wTq : (z == 1 ? wTk : (z == 2 ? wTv : wTo));
    K = 1024; N = 1024;
    k0 = (r & 31) * 32; n0 = (r >> 5) * 32;
  }
  __shared__ u16 t[32][33];
  int r = tid >> 3;
  int c = (tid & 7) << 2;
  float4 v = *(const float4*)(W + (size_t)(k0 + r) * N + n0 + c);
  t[r][c + 0] = f2bf(v.x); t[r][c + 1] = f2bf(v.y);
  t[r][c + 2] = f2bf(v.z); t[r][c + 3] = f2bf(v.w);
  __syncthreads();
  ushort4 o;
  o.x = t[c + 0][r]; o.y = t[c + 1][r]; o.z = t[c + 2][r]; o.w = t[c + 3][r];
  *(ushort4*)(WT + (size_t)(n0 + r) * K + k0 + c) = o;
}

// ---------------- GEMM 128x128, out bf16 + relu (+bias)  [ffn1] ------------
// launch_bounds(256,4): VGPR<=128 -> 4 blocks/CU -> 1024-block grid = 1 round
__global__ __launch_bounds__(256, 4) void gemm_bt_relu(
    const u16* __restrict__ A, const u16* __restrict__ BT,
    const float* __restrict__ bias, u16* __restrict__ outp,
    int M, int N, int K) {
  __shared__ __align__(16) u16 As[128 * 32];
  __shared__ __align__(16) u16 Bs[128 * 32];
  int tid = threadIdx.x;
  int lane = tid & 63;
  int wave = tid >> 6;
  int quad = lane >> 4;
  int l16 = lane & 15;
  int mt, nt;
  swizzle_mn(mt, nt);
  int m0 = mt * 128;
  int n0 = nt * 128;
  int wm = (wave >> 1) * 64;
  int wn = (wave & 1) * 64;

  f32x4 zero = {0.f, 0.f, 0.f, 0.f};
  f32x4 acc[4][4];
#pragma unroll
  for (int i = 0; i < 4; i++)
#pragma unroll
    for (int j = 0; j < 4; j++) acc[i][j] = zero;

  int c0 = tid, c1 = tid + 256;
  const u16* ga0 = A + (size_t)(m0 + (c0 >> 2)) * K + (c0 & 3) * 8;
  const u16* ga1 = A + (size_t)(m0 + (c1 >> 2)) * K + (c1 & 3) * 8;
  const u16* gb0 = BT + (size_t)(n0 + (c0 >> 2)) * K + (c0 & 3) * 8;
  const u16* gb1 = BT + (size_t)(n0 + (c1 >> 2)) * K + (c1 & 3) * 8;

  for (int k0 = 0; k0 < K; k0 += 32) {
    gload16(ga0 + k0, &As[c0 * 8]);
    gload16(ga1 + k0, &As[c1 * 8]);
    gload16(gb0 + k0, &Bs[c0 * 8]);
    gload16(gb1 + k0, &Bs[c1 * 8]);
    __syncthreads();
    bf16x8 af[4], bfr[4];
#pragma unroll
    for (int i = 0; i < 4; i++)
      af[i] = *(const bf16x8*)&As[(wm + i * 16 + l16) * 32 + quad * 8];
#pragma unroll
    for (int j = 0; j < 4; j++)
      bfr[j] = *(const bf16x8*)&Bs[(wn + j * 16 + l16) * 32 + quad * 8];
#pragma unroll
    for (int i = 0; i < 4; i++)
#pragma unroll
      for (int j = 0; j < 4; j++)
        acc[i][j] = mfma16(af[i], bfr[j], acc[i][j]);
    __syncthreads();
  }

#pragma unroll
  for (int j = 0; j < 4; j++) {
    int gcol = n0 + wn + j * 16 + l16;
    float bv = bias[gcol];
#pragma unroll
    for (int i = 0; i < 4; i++) {
#pragma unroll
      for (int r = 0; r < 4; r++) {
        int grow = m0 + wm + i * 16 + quad * 4 + r;
        float val = acc[i][j][r] + bv;
        outp[(size_t)grow * N + gcol] = f2bf(val > 0.f ? val : 0.f);
      }
    }
  }
}

// ---------------- GEMM 128x128 split-K (up to 4), separate fp32 outputs ----
__global__ __launch_bounds__(256, 4) void gemm_bt_sk4(
    const u16* __restrict__ A, const u16* __restrict__ BT,
    const float* __restrict__ bias,
    float* __restrict__ o0, float* __restrict__ o1,
    float* __restrict__ o2, float* __restrict__ o3,
    int M, int N, int K, int Kc) {
  __shared__ __align__(16) u16 As[128 * 32];
  __shared__ __align__(16) u16 Bs[128 * 32];
  int tid = threadIdx.x;
  int lane = tid & 63;
  int wave = tid >> 6;
  int quad = lane >> 4;
  int l16 = lane & 15;
  int mt, nt;
  swizzle_mn(mt, nt);
  int m0 = mt * 128;
  int n0 = nt * 128;
  int z = blockIdx.z;
  int kb = z * Kc;
  int wm = (wave >> 1) * 64;
  int wn = (wave & 1) * 64;

  f32x4 zero = {0.f, 0.f, 0.f, 0.f};
  f32x4 acc[4][4];
#pragma unroll
  for (int i = 0; i < 4; i++)
#pragma unroll
    for (int j = 0; j < 4; j++) acc[i][j] = zero;

  int c0 = tid, c1 = tid + 256;
  const u16* ga0 = A + (size_t)(m0 + (c0 >> 2)) * K + (c0 & 3) * 8 + kb;
  const u16* ga1 = A + (size_t)(m0 + (c1 >> 2)) * K + (c1 & 3) * 8 + kb;
  const u16* gb0 = BT + (size_t)(n0 + (c0 >> 2)) * K + (c0 & 3) * 8 + kb;
  const u16* gb1 = BT + (size_t)(n0 + (c1 >> 2)) * K + (c1 & 3) * 8 + kb;

  for (int k0 = 0; k0 < Kc; k0 += 32) {
    gload16(ga0 + k0, &As[c0 * 8]);
    gload16(ga1 + k0, &As[c1 * 8]);
    gload16(gb0 + k0, &Bs[c0 * 8]);
    gload16(gb1 + k0, &Bs[c1 * 8]);
    __syncthreads();
    bf16x8 af[4], bfr[4];
#pragma unroll
    for (int i = 0; i < 4; i++)
      af[i] = *(const bf16x8*)&As[(wm + i * 16 + l16) * 32 + quad * 8];
#pragma unroll
    for (int j = 0; j < 4; j++)
      bfr[j] = *(const bf16x8*)&Bs[(wn + j * 16 + l16) * 32 + quad * 8];
#pragma unroll
    for (int i = 0; i < 4; i++)
#pragma unroll
      for (int j = 0; j < 4; j++)
        acc[i][j] = mfma16(af[i], bfr[j], acc[i][j]);
    __syncthreads();
  }

  float* outz = z == 0 ? o0 : (z == 1 ? o1 : (z == 2 ? o2 : o3));
  float biasmul = (z == 0) ? 1.f : 0.f;
#pragma unroll
  for (int j = 0; j < 4; j++) {
    int gcol = n0 + wn + j * 16 + l16;
    float bv = bias[gcol] * biasmul;
#pragma unroll
    for (int i = 0; i < 4; i++) {
#pragma unroll
      for (int r = 0; r < 4; r++) {
        int grow = m0 + wm + i * 16 + quad * 4 + r;
        outz[(size_t)grow * N + gcol] = acc[i][j][r] + bv;
      }
    }
  }
}

// ---------------- fused QKV GEMM (q pre-scaled by 1/sqrt(HD)*log2e) --------
__global__ __launch_bounds__(256) void gemm_qkv(
    const u16* __restrict__ A, const u16* __restrict__ BT,
    const float* __restrict__ bq, const float* __restrict__ bk,
    const float* __restrict__ bvp,
    u16* __restrict__ qb, u16* __restrict__ kb, u16* __restrict__ vb) {
  const int K = 1024;
  __shared__ __align__(16) u16 As[128 * 32];
  __shared__ __align__(16) u16 Bs[128 * 32];
  int tid = threadIdx.x;
  int lane = tid & 63;
  int wave = tid >> 6;
  int quad = lane >> 4;
  int l16 = lane & 15;
  int mt, nt;
  swizzle_mn(mt, nt);
  int m0 = mt * 128;
  int n0 = nt * 128;
  int wm = (wave >> 1) * 64;
  int wn = (wave & 1) * 64;

  f32x4 zero = {0.f, 0.f, 0.f, 0.f};
  f32x4 acc[4][4];
#pragma unroll
  for (int i = 0; i < 4; i++)
#pragma unroll
    for (int j = 0; j < 4; j++) acc[i][j] = zero;

  int c0 = tid, c1 = tid + 256;
  const u16* ga0 = A + (size_t)(m0 + (c0 >> 2)) * K + (c0 & 3) * 8;
  const u16* ga1 = A + (size_t)(m0 + (c1 >> 2)) * K + (c1 & 3) * 8;
  const u16* gb0 = BT + (size_t)(n0 + (c0 >> 2)) * K + (c0 & 3) * 8;
  const u16* gb1 = BT + (size_t)(n0 + (c1 >> 2)) * K + (c1 & 3) * 8;

  for (int k0 = 0; k0 < K; k0 += 32) {
    gload16(ga0 + k0, &As[c0 * 8]);
    gload16(ga1 + k0, &As[c1 * 8]);
    gload16(gb0 + k0, &Bs[c0 * 8]);
    gload16(gb1 + k0, &Bs[c1 * 8]);
    __syncthreads();
    bf16x8 af[4], bfr[4];
#pragma unroll
    for (int i = 0; i < 4; i++)
      af[i] = *(const bf16x8*)&As[(wm + i * 16 + l16) * 32 + quad * 8];
#pragma unroll
    for (int j = 0; j < 4; j++)
      bfr[j] = *(const bf16x8*)&Bs[(wn + j * 16 + l16) * 32 + quad * 8];
#pragma unroll
    for (int i = 0; i < 4; i++)
#pragma unroll
      for (int j = 0; j < 4; j++)
        acc[i][j] = mfma16(af[i], bfr[j], acc[i][j]);
    __syncthreads();
  }

  int region = n0 >> 10;
  const float* bias = region == 0 ? bq : (region == 1 ? bk : bvp);
  u16* outp = region == 0 ? qb : (region == 1 ? kb : vb);
  float scale = region == 0 ? 0.125f * 1.4426950408889634f : 1.f;

#pragma unroll
  for (int j = 0; j < 4; j++) {
    int gcol = (n0 & 1023) + wn + j * 16 + l16;
    float bv = bias[gcol];
    int h = gcol >> 6, hd = gcol & 63;
#pragma unroll
    for (int i = 0; i < 4; i++) {
#pragma unroll
      for (int r = 0; r < 4; r++) {
        int grow = m0 + wm + i * 16 + quad * 4 + r;
        float val = (acc[i][j][r] + bv) * scale;
        int b = grow >> 11, s = grow & 2047;
        if (region < 2) {
          outp[(((size_t)(b * H_ + h)) * S_ + s) * HD_ + hd] = f2bf(val);
        } else {
          outp[(((size_t)(b * H_ + h)) * HD_ + hd) * S_ + s] = f2bf(val);
        }
      }
    }
  }
}

// ---------------- flash attention: MQ=32/wave, double-buffered K/V ---------
// (unchanged from R7 — isolating the GEMM experiment)
__global__ __launch_bounds__(256, 2) void attn_kernel(
    const u16* __restrict__ q, const u16* __restrict__ k,
    const u16* __restrict__ vt, const int* __restrict__ mask,
    u16* __restrict__ ao) {
  __shared__ __align__(16) u16 Ks[2][64 * 72];
  __shared__ __align__(16) u16 Vs[2][64 * 72];
  __shared__ __align__(16) u16 Ps[4][32 * 72];
  int tid = threadIdx.x;
  int lane = tid & 63;
  int wave = tid >> 6;
  int quad = lane >> 4;
  int l16 = lane & 15;
  int bh = blockIdx.y;
  int b = bh >> 4;
  int h = bh & 15;
  int qrow0 = blockIdx.x * 128 + wave * 32;

  const u16* qh = q + (size_t)bh * S_ * HD_;
  const u16* kh = k + (size_t)bh * S_ * HD_;
  const u16* vh = vt + (size_t)bh * HD_ * S_;

  bf16x8 qfA0 = *(const bf16x8*)(qh + (size_t)(qrow0 + l16) * HD_ + quad * 8);
  bf16x8 qfA1 = *(const bf16x8*)(qh + (size_t)(qrow0 + l16) * HD_ + 32 + quad * 8);
  bf16x8 qfB0 = *(const bf16x8*)(qh + (size_t)(qrow0 + 16 + l16) * HD_ + quad * 8);
  bf16x8 qfB1 = *(const bf16x8*)(qh + (size_t)(qrow0 + 16 + l16) * HD_ + 32 + quad * 8);

  int sr = tid >> 3, sc = tid & 7;
  const u16* kg0 = kh + sr * HD_ + sc * 8;
  const u16* kg1 = kh + (sr + 32) * HD_ + sc * 8;
  const u16* vg0 = vh + (size_t)sr * S_ + sc * 8;
  const u16* vg1 = vh + (size_t)(sr + 32) * S_ + sc * 8;
  int kr0 = (sr & 1) * 16 + (sr >> 1);
  int ko0 = kr0 * 72 + sc * 8;
  int ko1 = (32 + kr0) * 72 + sc * 8;
  int vo0 = sr * 72 + sc * 8;
  int vo1 = (sr + 32) * 72 + sc * 8;
  const int* mrow = mask + b * S_ + 2 * l16;

  float l_pA[4] = {0.f, 0.f, 0.f, 0.f};
  float l_pB[4] = {0.f, 0.f, 0.f, 0.f};
  f32x4 zero = {0.f, 0.f, 0.f, 0.f};
  f32x4 o_accA[4], o_accB[4];
#pragma unroll
  for (int c = 0; c < 4; c++) { o_accA[c] = zero; o_accB[c] = zero; }

  u16* pw = &Ps[wave][0];

  bf16x8 kv0 = *(const bf16x8*)(kg0);
  bf16x8 kv1 = *(const bf16x8*)(kg1);
  bf16x8 vv0 = *(const bf16x8*)(vg0);
  bf16x8 vv1 = *(const bf16x8*)(vg1);
  *(bf16x8*)&Ks[0][ko0] = kv0;
  *(bf16x8*)&Ks[0][ko1] = kv1;
  *(bf16x8*)&Vs[0][vo0] = vv0;
  *(bf16x8*)&Vs[0][vo1] = vv1;
  kv0 = *(const bf16x8*)(kg0 + (size_t)64 * HD_);
  kv1 = *(const bf16x8*)(kg1 + (size_t)64 * HD_);
  vv0 = *(const bf16x8*)(vg0 + 64);
  vv1 = *(const bf16x8*)(vg1 + 64);

  int cur = 0;
  for (int kt = 0; kt < S_; kt += 64) {
    int2 mk0 = *(const int2*)(mrow + kt);
    int2 mk1 = *(const int2*)(mrow + kt + 32);

    __syncthreads();
    if (kt + 64 < S_) {
      int alt = cur ^ 1;
      *(bf16x8*)&Ks[alt][ko0] = kv0;
      *(bf16x8*)&Ks[alt][ko1] = kv1;
      *(bf16x8*)&Vs[alt][vo0] = vv0;
      *(bf16x8*)&Vs[alt][vo1] = vv1;
      int nk = (kt + 128) & (S_ - 1);
      kv0 = *(const bf16x8*)(kg0 + (size_t)nk * HD_);
      kv1 = *(const bf16x8*)(kg1 + (size_t)nk * HD_);
      vv0 = *(const bf16x8*)(vg0 + nk);
      vv1 = *(const bf16x8*)(vg1 + nk);
    }

    const u16* ksb = &Ks[cur][0];
    const u16* vsb = &Vs[cur][0];
#pragma unroll
    for (int g = 0; g < 2; g++) {
      int2 mk = g == 0 ? mk0 : mk1;
      int rowe = (g * 32 + l16) * 72;
      int rowo = (g * 32 + 16 + l16) * 72;
      bf16x8 e0 = *(const bf16x8*)&ksb[rowe + quad * 8];
      bf16x8 e1 = *(const bf16x8*)&ksb[rowe + 32 + quad * 8];
      bf16x8 o0 = *(const bf16x8*)&ksb[rowo + quad * 8];
      bf16x8 o1 = *(const bf16x8*)&ksb[rowo + 32 + quad * 8];
      f32x4 seA = mfma16(qfA1, e1, mfma16(qfA0, e0, zero));
      f32x4 soA = mfma16(qfA1, o1, mfma16(qfA0, o0, zero));
      f32x4 seB = mfma16(qfB1, e1, mfma16(qfB0, e0, zero));
      f32x4 soB = mfma16(qfB1, o1, mfma16(qfB0, o0, zero));
#pragma unroll
      for (int r = 0; r < 4; r++) {
        float pA0 = mk.x ? exp2f(seA[r]) : 0.f;
        float pA1 = mk.y ? exp2f(soA[r]) : 0.f;
        float pB0 = mk.x ? exp2f(seB[r]) : 0.f;
        float pB1 = mk.y ? exp2f(soB[r]) : 0.f;
        l_pA[r] += pA0 + pA1;
        l_pB[r] += pB0 + pB1;
        unsigned pkA = __builtin_amdgcn_perm(__float_as_uint(pA1),
                                             __float_as_uint(pA0), 0x07060302u);
        unsigned pkB = __builtin_amdgcn_perm(__float_as_uint(pB1),
                                             __float_as_uint(pB0), 0x07060302u);
        *(unsigned*)&pw[(quad * 4 + r) * 72 + g * 32 + 2 * l16] = pkA;
        *(unsigned*)&pw[(16 + quad * 4 + r) * 72 + g * 32 + 2 * l16] = pkB;
      }
    }
    bf16x8 pfA0 = *(const bf16x8*)&pw[l16 * 72 + quad * 8];
    bf16x8 pfA1 = *(const bf16x8*)&pw[l16 * 72 + 32 + quad * 8];
    bf16x8 pfB0 = *(const bf16x8*)&pw[(16 + l16) * 72 + quad * 8];
    bf16x8 pfB1 = *(const bf16x8*)&pw[(16 + l16) * 72 + 32 + quad * 8];
#pragma unroll
    for (int c = 0; c < 4; c++) {
      bf16x8 vf0 = *(const bf16x8*)&vsb[(c * 16 + l16) * 72 + quad * 8];
      bf16x8 vf1 = *(const bf16x8*)&vsb[(c * 16 + l16) * 72 + 32 + quad * 8];
      o_accA[c] = mfma16(pfA1, vf1, mfma16(pfA0, vf0, o_accA[c]));
      o_accB[c] = mfma16(pfB1, vf1, mfma16(pfB0, vf0, o_accB[c]));
    }
    cur ^= 1;
  }

#pragma unroll
  for (int r = 0; r < 4; r++) {
    float sA = l_pA[r], sB = l_pB[r];
#pragma unroll
    for (int off = 1; off < 16; off <<= 1) {
      sA += __shfl_xor(sA, off);
      sB += __shfl_xor(sB, off);
    }
    float invA = 1.f / sA, invB = 1.f / sB;
    int srowA = qrow0 + quad * 4 + r;
    int srowB = qrow0 + 16 + quad * 4 + r;
#pragma unroll
    for (int c = 0; c < 4; c++) {
      ao[((size_t)(b * S_ + srowA)) * D_ + h * HD_ + c * 16 + l16] =
          f2bf(o_accA[c][r] * invA);
      ao[((size_t)(b * S_ + srowB)) * D_ + h * HD_ + c * 16 + l16] =
          f2bf(o_accB[c][r] * invB);
    }
  }
}

// ---------------- residual (2 partials) + layernorm ----------------
__global__ __launch_bounds__(256) void ln_kernel(
    const float* __restrict__ xa, const float* __restrict__ add0,
    const float* __restrict__ add1,
    const float* __restrict__ g, const float* __restrict__ be,
    float* __restrict__ outf, u16* __restrict__ outb) {
  int row = blockIdx.x;
  int tid = threadIdx.x;
  int lane = tid & 63;
  int wv = tid >> 6;
  const float4 a = *(const float4*)(xa + (size_t)row * D_ + tid * 4);
  const float4 c = *(const float4*)(add0 + (size_t)row * D_ + tid * 4);
  const float4 d = *(const float4*)(add1 + (size_t)row * D_ + tid * 4);
  float v0 = a.x + c.x + d.x, v1 = a.y + c.y + d.y;
  float v2 = a.z + c.z + d.z, v3 = a.w + c.w + d.w;
  float s = v0 + v1 + v2 + v3;
  float sq = v0 * v0 + v1 * v1 + v2 * v2 + v3 * v3;
#pragma unroll
  for (int off = 1; off < 64; off <<= 1) {
    s += __shfl_xor(s, off);
    sq += __shfl_xor(sq, off);
  }
  __shared__ float red[8];
  if (lane == 0) { red[wv] = s; red[4 + wv] = sq; }
  __syncthreads();
  s = red[0] + red[1] + red[2] + red[3];
  sq = red[4] + red[5] + red[6] + red[7];
  float mean = s * (1.f / D_);
  float var = sq * (1.f / D_) - mean * mean;
  float rstd = rsqrtf(var + 1e-5f);
  const float4 gv = *(const float4*)(g + tid * 4);
  const float4 bv = *(const float4*)(be + tid * 4);
  float y0 = (v0 - mean) * rstd * gv.x + bv.x;
  float y1 = (v1 - mean) * rstd * gv.y + bv.y;
  float y2 = (v2 - mean) * rstd * gv.z + bv.z;
  float y3 = (v3 - mean) * rstd * gv.w + bv.w;
  float4 o = {y0, y1, y2, y3};
  *(float4*)(outf + (size_t)row * D_ + tid * 4) = o;
  if (outb) {
    ushort4 ob = {f2bf(y0), f2bf(y1), f2bf(y2), f2bf(y3)};
    *(ushort4*)(outb + (size_t)row * D_ + tid * 4) = ob;
  }
}

// ---------------- residual (4 partials) + layernorm ----------------
__global__ __launch_bounds__(256) void ln4_kernel(
    const float* __restrict__ xa,
    const float* __restrict__ a0, const float* __restrict__ a1,
    const float* __restrict__ a2, const float* __restrict__ a3,
    const float* __restrict__ g, const float* __restrict__ be,
    float* __restrict__ outf, u16* __restrict__ outb) {
  int row = blockIdx.x;
  int tid = threadIdx.x;
  int lane = tid & 63;
  int wv = tid >> 6;
  size_t off0 = (size_t)row * D_ + tid * 4;
  const float4 a = *(const float4*)(xa + off0);
  const float4 c0 = *(const float4*)(a0 + off0);
  const float4 c1 = *(const float4*)(a1 + off0);
  const float4 c2 = *(const float4*)(a2 + off0);
  const float4 c3 = *(const float4*)(a3 + off0);
  float v0 = a.x + (c0.x + c1.x) + (c2.x + c3.x);
  float v1 = a.y + (c0.y + c1.y) + (c2.y + c3.y);
  float v2 = a.z + (c0.z + c1.z) + (c2.z + c3.z);
  float v3 = a.w + (c0.w + c1.w) + (c2.w + c3.w);
  float s = v0 + v1 + v2 + v3;
  float sq = v0 * v0 + v1 * v1 + v2 * v2 + v3 * v3;
#pragma unroll
  for (int off = 1; off < 64; off <<= 1) {
    s += __shfl_xor(s, off);
    sq += __shfl_xor(sq, off);
  }
  __shared__ float red[8];
  if (lane == 0) { red[wv] = s; red[4 + wv] = sq; }
  __syncthreads();
  s = red[0] + red[1] + red[2] + red[3];
  sq = red[4] + red[5] + red[6] + red[7];
  float mean = s * (1.f / D_);
  float var = sq * (1.f / D_) - mean * mean;
  float rstd = rsqrtf(var + 1e-5f);
  const float4 gv = *(const float4*)(g + tid * 4);
  const float4 bv = *(const float4*)(be + tid * 4);
  float y0 = (v0 - mean) * rstd * gv.x + bv.x;
  float y1 = (v1 - mean) * rstd * gv.y + bv.y;
  float y2 = (v2 - mean) * rstd * gv.z + bv.z;
  float y3 = (v3 - mean) * rstd * gv.w + bv.w;
  float4 o = {y0, y1, y2, y3};
  *(float4*)(outf + off0) = o;
  if (outb) {
    ushort4 ob = {f2bf(y0), f2bf(y1), f2bf(y2), f2bf(y3)};
    *(ushort4*)(outb + off0) = ob;
  }
}

extern "C" void kernel_launch(void* const* d_in, const int* in_sizes, int n_in,
                              void* d_out, int out_size, void* d_ws, size_t ws_size,
                              hipStream_t stream) {
  const float* x = (const float*)d_in[0];
  const int* mask = (const int*)d_in[1];
  const float* Wq = (const float*)d_in[2];
  const float* bq = (const float*)d_in[3];
  const float* Wk = (const float*)d_in[4];
  const float* bk = (const float*)d_in[5];
  const float* Wv = (const float*)d_in[6];
  const float* bv = (const float*)d_in[7];
  const float* Wo = (const float*)d_in[8];
  const float* bo = (const float*)d_in[9];
  const float* W1 = (const float*)d_in[10];
  const float* b1 = (const float*)d_in[11];
  const float* W2 = (const float*)d_in[12];
  const float* b2 = (const float*)d_in[13];
  const float* g1 = (const float*)d_in[14];
  const float* be1 = (const float*)d_in[15];
  const float* g2 = (const float*)d_in[16];
  const float* be2 = (const float*)d_in[17];

  const size_t MB = 1ull << 20;
  char* ws = (char*)d_ws;
  u16* wTq = (u16*)(ws + 0 * MB);   // [wTq;wTk;wTv] contiguous = fused QKV BT
  u16* wTk = (u16*)(ws + 2 * MB);
  u16* wTv = (u16*)(ws + 4 * MB);
  u16* wTo = (u16*)(ws + 6 * MB);
  u16* w1T = (u16*)(ws + 8 * MB);   // FF x D
  u16* w2T = (u16*)(ws + 16 * MB);  // D x FF (live through ffn2)
  u16* xb  = (u16*)(ws + 24 * MB);
  u16* qb  = (u16*)(ws + 32 * MB);
  u16* kb  = (u16*)(ws + 40 * MB);
  u16* vb  = (u16*)(ws + 48 * MB);
  u16* ao  = (u16*)(ws + 56 * MB);
  float* p0 = (float*)(ws + 64 * MB);    // proj partials (sk2): 64..96
  float* p1 = (float*)(ws + 80 * MB);
  float* x1f = (float*)(ws + 24 * MB);   // reuse xb+qb (dead after attn)
  u16*   x1b = (u16*)(ws + 40 * MB);     // reuse kb (dead after attn)
  u16*   h1  = (u16*)(ws + 48 * MB);     // 48..80 (vb/ao/p0 dead after LN1)
  float* f0 = (float*)(ws + 80 * MB);    // ffn2 partials (sk4)
  float* f1 = (float*)(ws + 96 * MB);
  float* f2 = (float*)(ws + 112 * MB);
  float* f3 = (float*)(ws + 0 * MB);     // weights 0..16 dead by ffn2 time

  // fused prep (x cvt + all 6 weight transposes) — 1 launch
  prep_kernel<<<dim3(16384), dim3(256), 0, stream>>>(
      x, xb, W1, w1T, W2, w2T, Wq, Wk, Wv, Wo, wTq, wTk, wTv, wTo);

  gemm_qkv<<<dim3(32, 24), dim3(256), 0, stream>>>(xb, wTq, bq, bk, bv, qb, kb, vb);

  attn_kernel<<<dim3(S_ / 128, B_ * H_), dim3(256), 0, stream>>>(qb, kb, vb, mask, ao);

  // proj: split-K x2 (512 blocks), partials p0,p1
  gemm_bt_sk4<<<dim3(32, 8, 2), dim3(256), 0, stream>>>(
      ao, wTo, bo, p0, p1, p0, p0, 4096, 1024, 1024, 512);

  ln_kernel<<<dim3(4096), dim3(256), 0, stream>>>(x, p0, p1, g1, be1, x1f, x1b);

  gemm_bt_relu<<<dim3(32, 32), dim3(256), 0, stream>>>(x1b, w1T, b1, h1, 4096, 4096, 1024);

  // ffn2: split-K x4 (1024 blocks, 4/CU with launch_bounds), partials f0..f3
  gemm_bt_sk4<<<dim3(32, 8, 4), dim3(256), 0, stream>>>(
      h1, w2T, b2, f0, f1, f2, f3, 4096, 1024, 4096, 1024);

  ln4_kernel<<<dim3(4096), dim3(256), 0, stream>>>(
      x1f, f0, f1, f2, f3, g2, be2, (float*)d_out, (u16*)nullptr);
}